// Round 1
// baseline (422.495 us; speedup 1.0000x reference)
//
#include <hip/hip_runtime.h>
#include <hip/hip_bf16.h>
#include <math.h>

// Problem constants
#define NN 50000
#define INF_ 128
#define D1 256      // combined xl|xr width layer 1
#define D2 80       // combined xl|xr width layer 2
#define EE 800000

// ---------------- workspace layout (bytes) ----------------
// all chunks 256B-aligned
#define OFF_XLR1 ((size_t)0)                       // N*256 f32 = 51,200,000
#define SZ_XLR1  ((size_t)NN * 256 * 4)
#define OFF_H1   (OFF_XLR1 + SZ_XLR1)              // N*128 f32 = 25,600,000
#define SZ_H1    ((size_t)NN * 128 * 4)
#define OFF_XLR2 (OFF_H1 + SZ_H1)                  // N*80 f32 = 16,000,000
#define SZ_XLR2  ((size_t)NN * 80 * 4)
#define OFF_WB1  (OFF_XLR2 + SZ_XLR2)              // 128*256 f32
#define SZ_WB1   ((size_t)128 * 256 * 4)
#define OFF_BB1  (OFF_WB1 + SZ_WB1)                // 256 f32
#define SZ_BB1   ((size_t)1024)
#define OFF_WB2  (OFF_BB1 + SZ_BB1)                // 128*80 f32
#define SZ_WB2   ((size_t)128 * 80 * 4)
#define OFF_BB2  (OFF_WB2 + SZ_WB2)                // 80 f32 (pad to 512)
#define SZ_BB2   ((size_t)512)
#define OFF_DEG  (OFF_BB2 + SZ_BB2)                // N int
#define SZ_DEG   ((size_t)NN * 4)
#define OFF_OFFS (OFF_DEG + SZ_DEG)                // (N+1) int (pad)
#define SZ_OFFS  ((size_t)((NN + 1) * 4 + 252) / 256 * 256)
#define OFF_CUR  (OFF_OFFS + SZ_OFFS)              // N int
#define SZ_CUR   ((size_t)NN * 4)
#define OFF_CSR  (OFF_CUR + SZ_CUR)                // E int
#define SZ_CSR   ((size_t)EE * 4)

// ---------------- small utility kernels ----------------
__global__ void zero_int_kernel(int* __restrict__ p, int n) {
    int i = blockIdx.x * blockDim.x + threadIdx.x;
    if (i < n) p[i] = 0;
}

__global__ void pack_weights_kernel(
    const float* __restrict__ Wl1, const float* __restrict__ bl1,
    const float* __restrict__ Wr1, const float* __restrict__ br1,
    const float* __restrict__ Wl2, const float* __restrict__ bl2,
    const float* __restrict__ Wr2, const float* __restrict__ br2,
    float* __restrict__ WB1, float* __restrict__ BB1,
    float* __restrict__ WB2, float* __restrict__ BB2) {
    int i = blockIdx.x * blockDim.x + threadIdx.x;
    if (i < 128 * 256) {
        int k = i >> 8, j = i & 255;
        WB1[i] = (j < 128) ? Wl1[k * 128 + j] : Wr1[k * 128 + j - 128];
    }
    if (i < 256) BB1[i] = (i < 128) ? bl1[i] : br1[i - 128];
    if (i < 128 * 80) {
        int k = i / 80, j = i % 80;
        WB2[i] = (j < 40) ? Wl2[k * 40 + j] : Wr2[k * 40 + j - 40];
    }
    if (i < 80) BB2[i] = (i < 40) ? bl2[i] : br2[i - 40];
}

__global__ void hist_kernel(const int* __restrict__ tgts, int* __restrict__ deg, int e_) {
    int e = blockIdx.x * blockDim.x + threadIdx.x;
    if (e < e_) atomicAdd(&deg[tgts[e]], 1);
}

// single-block inclusive scan over deg -> off[N+1], cur[i]=off[i]
__global__ __launch_bounds__(1024) void scan_kernel(
    const int* __restrict__ deg, int* __restrict__ off, int* __restrict__ cur, int n) {
    __shared__ int wsum[16];
    int carry = 0;
    int lane = threadIdx.x & 63, w = threadIdx.x >> 6;
    if (threadIdx.x == 0) off[0] = 0;
    for (int base = 0; base < n; base += 1024) {
        __syncthreads();  // protect wsum reuse across chunks
        int i = base + threadIdx.x;
        int v = (i < n) ? deg[i] : 0;
        int incl = v;
#pragma unroll
        for (int d = 1; d < 64; d <<= 1) {
            int t = __shfl_up(incl, d, 64);
            if (lane >= d) incl += t;
        }
        if (lane == 63) wsum[w] = incl;
        __syncthreads();
        if (threadIdx.x < 16) {
            int x = wsum[threadIdx.x];
#pragma unroll
            for (int d = 1; d < 16; d <<= 1) {
                int t = __shfl_up(x, d, 16);
                if ((int)threadIdx.x >= d) x += t;
            }
            wsum[threadIdx.x] = x;
        }
        __syncthreads();
        int add = (w > 0) ? wsum[w - 1] : 0;
        int inclTot = incl + add;
        if (i < n) {
            off[i + 1] = carry + inclTot;
            cur[i] = carry + inclTot - v;
        }
        carry += wsum[15];
    }
}

__global__ void scatter_kernel(const int* __restrict__ srcs, const int* __restrict__ tgts,
                               int* __restrict__ cur, int* __restrict__ csr, int e_) {
    int e = blockIdx.x * blockDim.x + threadIdx.x;
    if (e < e_) {
        int t = tgts[e];
        int pos = atomicAdd(&cur[t], 1);
        csr[pos] = srcs[e];
    }
}

// ---------------- f32 GEMM: C[M,N] = A[M,K] @ B[K,N] + bias[N] ----------------
// BM=64 BN=64 BK=16, 256 threads, 4x4 micro-tile
__global__ __launch_bounds__(256) void gemm_bias_kernel(
    const float* __restrict__ A, const float* __restrict__ B,
    const float* __restrict__ bias, float* __restrict__ C,
    int M, int N, int K) {
    __shared__ float As[16][68];  // [k][row], padded: 2-way bank conflict max, 16B-aligned rows
    __shared__ float Bs[16][64];  // [k][col]
    int tid = threadIdx.x;
    int r0 = blockIdx.y * 64;
    int n0 = blockIdx.x * 64;
    int trow = tid >> 4, tcol = tid & 15;
    int arow = tid >> 2;            // 0..63
    int akq = (tid & 3) << 2;       // 0,4,8,12
    int bk = tid >> 4;              // 0..15
    int bnq = (tid & 15) << 2;      // 0..60
    float acc[4][4] = {};
    for (int k0 = 0; k0 < K; k0 += 16) {
        float4 av = make_float4(0.f, 0.f, 0.f, 0.f);
        if (r0 + arow < M) av = *(const float4*)&A[(size_t)(r0 + arow) * K + k0 + akq];
        As[akq + 0][arow] = av.x;
        As[akq + 1][arow] = av.y;
        As[akq + 2][arow] = av.z;
        As[akq + 3][arow] = av.w;
        float4 bv;
        int bn = n0 + bnq;
        if (bn + 3 < N) {
            bv = *(const float4*)&B[(size_t)(k0 + bk) * N + bn];
        } else {
            float t0 = (bn + 0 < N) ? B[(size_t)(k0 + bk) * N + bn + 0] : 0.f;
            float t1 = (bn + 1 < N) ? B[(size_t)(k0 + bk) * N + bn + 1] : 0.f;
            float t2 = (bn + 2 < N) ? B[(size_t)(k0 + bk) * N + bn + 2] : 0.f;
            float t3 = (bn + 3 < N) ? B[(size_t)(k0 + bk) * N + bn + 3] : 0.f;
            bv = make_float4(t0, t1, t2, t3);
        }
        *(float4*)&Bs[bk][bnq] = bv;
        __syncthreads();
#pragma unroll
        for (int k = 0; k < 16; ++k) {
            float4 a = *(const float4*)&As[k][trow << 2];
            float4 b = *(const float4*)&Bs[k][tcol << 2];
            float ar[4] = {a.x, a.y, a.z, a.w};
            float br[4] = {b.x, b.y, b.z, b.w};
#pragma unroll
            for (int i = 0; i < 4; ++i)
#pragma unroll
                for (int j = 0; j < 4; ++j) acc[i][j] = fmaf(ar[i], br[j], acc[i][j]);
        }
        __syncthreads();
    }
#pragma unroll
    for (int i = 0; i < 4; ++i) {
        int r = r0 + (trow << 2) + i;
        if (r >= M) break;
#pragma unroll
        for (int j = 0; j < 4; ++j) {
            int c = n0 + (tcol << 2) + j;
            if (c < N) C[(size_t)r * N + c] = acc[i][j] + bias[c];
        }
    }
}

// ---------------- layer-1 fused edge kernel ----------------
// one wave per node. XLR layout: [node][0:128]=xl, [node][128:256]=xr
// lane holds channels c0=lane, c1=lane+64. Online segment softmax + aggregate,
// then bias + LayerNorm + ELU fused. Output H1[N,128].
__global__ __launch_bounds__(256) void gat_edge1_kernel(
    const float* __restrict__ XLR, const int* __restrict__ off, const int* __restrict__ csr,
    const float* __restrict__ att, const float* __restrict__ b1,
    const float* __restrict__ g1, const float* __restrict__ be1,
    float* __restrict__ H1) {
    int wid = threadIdx.x >> 6;
    int lane = threadIdx.x & 63;
    int node = blockIdx.x * 4 + wid;
    if (node >= NN) return;
    int c0 = lane, c1 = lane + 64;
    const size_t nb = (size_t)node * 256;
    float xr0 = XLR[nb + 128 + c0];
    float xr1 = XLR[nb + 128 + c1];
    float at0 = att[c0], at1 = att[c1];
    float m0 = -INFINITY, m1 = -INFINITY;
    float s0 = 0.f, s1 = 0.f, a0 = 0.f, a1 = 0.f;
    int jb = off[node], je = off[node + 1];
    for (int j0 = jb; j0 < je; j0 += 64) {
        int nsrc = min(64, je - j0);
        int my = (lane < nsrc) ? csr[j0 + lane] : 0;
        for (int k = 0; k < nsrc; ++k) {
            int sidx = __shfl(my, k, 64);
            size_t sb = (size_t)sidx * 256;
            float xl0 = XLR[sb + c0];
            float xl1 = XLR[sb + c1];
            float h0 = xl0 + xr0, h1v = xl1 + xr1;
            float t0 = (h0 > 0.f ? h0 : 0.2f * h0) * at0;
            float t1 = (h1v > 0.f ? h1v : 0.2f * h1v) * at1;
            // per-head reduce: heads live in 32-lane halves (slot0: h0/h1, slot1: h2/h3)
#pragma unroll
            for (int d = 16; d >= 1; d >>= 1) {
                t0 += __shfl_xor(t0, d, 32);
                t1 += __shfl_xor(t1, d, 32);
            }
            float nm0 = fmaxf(m0, t0), nm1 = fmaxf(m1, t1);
            float sc0 = __expf(m0 - nm0), sc1 = __expf(m1 - nm1);
            float p0 = __expf(t0 - nm0), p1 = __expf(t1 - nm1);
            a0 = a0 * sc0 + p0 * xl0;
            a1 = a1 * sc1 + p1 * xl1;
            s0 = s0 * sc0 + p0;
            s1 = s1 * sc1 + p1;
            m0 = nm0;
            m1 = nm1;
        }
    }
    float o0 = a0 / (s0 + 1e-16f) + b1[c0];
    float o1 = a1 / (s1 + 1e-16f) + b1[c1];
    // LayerNorm over 128 channels (2 per lane, wave reduce)
    float sum = o0 + o1, sq = o0 * o0 + o1 * o1;
#pragma unroll
    for (int d = 32; d >= 1; d >>= 1) {
        sum += __shfl_xor(sum, d, 64);
        sq += __shfl_xor(sq, d, 64);
    }
    float mu = sum * (1.f / 128.f);
    float var = sq * (1.f / 128.f) - mu * mu;
    float rs = rsqrtf(var + 1e-5f);
    float y0 = (o0 - mu) * rs * g1[c0] + be1[c0];
    float y1 = (o1 - mu) * rs * g1[c1] + be1[c1];
    y0 = y0 > 0.f ? y0 : expm1f(y0);
    y1 = y1 > 0.f ? y1 : expm1f(y1);
    H1[(size_t)node * 128 + c0] = y0;
    H1[(size_t)node * 128 + c1] = y1;
}

// ---------------- layer-2 fused edge kernel ----------------
// one wave per node, single head, C=40 (lanes 0..39 active for channels).
// XLR2 layout: [node][0:40]=xl, [node][40:80]=xr. Output d_out[N,40].
__global__ __launch_bounds__(256) void gat_edge2_kernel(
    const float* __restrict__ XLR2, const int* __restrict__ off, const int* __restrict__ csr,
    const float* __restrict__ att2, const float* __restrict__ b2,
    float* __restrict__ Y) {
    int wid = threadIdx.x >> 6;
    int lane = threadIdx.x & 63;
    int node = blockIdx.x * 4 + wid;
    if (node >= NN) return;
    bool act = lane < 40;
    const size_t nb = (size_t)node * 80;
    float xr = act ? XLR2[nb + 40 + lane] : 0.f;
    float at = act ? att2[lane] : 0.f;
    float m = -INFINITY, s = 0.f, a = 0.f;
    int jb = off[node], je = off[node + 1];
    for (int j0 = jb; j0 < je; j0 += 64) {
        int nsrc = min(64, je - j0);
        int my = (lane < nsrc) ? csr[j0 + lane] : 0;
        for (int k = 0; k < nsrc; ++k) {
            int sidx = __shfl(my, k, 64);
            float xl = act ? XLR2[(size_t)sidx * 80 + lane] : 0.f;
            float h = xl + xr;
            float t = (h > 0.f ? h : 0.2f * h) * at;
#pragma unroll
            for (int d = 32; d >= 1; d >>= 1) t += __shfl_xor(t, d, 64);
            float nm = fmaxf(m, t);
            float sc = __expf(m - nm), p = __expf(t - nm);
            a = a * sc + p * xl;
            s = s * sc + p;
            m = nm;
        }
    }
    if (act) Y[(size_t)node * 40 + lane] = a / (s + 1e-16f) + b2[lane];
}

// ---------------- launch ----------------
extern "C" void kernel_launch(void* const* d_in, const int* in_sizes, int n_in,
                              void* d_out, int out_size, void* d_ws, size_t ws_size,
                              hipStream_t stream) {
    const float* x = (const float*)d_in[0];
    const int* ei = (const int*)d_in[1];
    const float* Wl1 = (const float*)d_in[2];
    const float* bl1 = (const float*)d_in[3];
    const float* Wr1 = (const float*)d_in[4];
    const float* br1 = (const float*)d_in[5];
    const float* att1 = (const float*)d_in[6];
    const float* b1 = (const float*)d_in[7];
    const float* g1 = (const float*)d_in[8];
    const float* be1 = (const float*)d_in[9];
    const float* Wl2 = (const float*)d_in[10];
    const float* bl2 = (const float*)d_in[11];
    const float* Wr2 = (const float*)d_in[12];
    const float* br2 = (const float*)d_in[13];
    const float* att2 = (const float*)d_in[14];
    const float* b2 = (const float*)d_in[15];

    const int* srcs = ei;        // edge_index[0][:]
    const int* tgts = ei + EE;   // edge_index[1][:]

    char* ws = (char*)d_ws;
    float* XLR1 = (float*)(ws + OFF_XLR1);
    float* H1 = (float*)(ws + OFF_H1);
    float* XLR2 = (float*)(ws + OFF_XLR2);
    float* WB1 = (float*)(ws + OFF_WB1);
    float* BB1 = (float*)(ws + OFF_BB1);
    float* WB2 = (float*)(ws + OFF_WB2);
    float* BB2 = (float*)(ws + OFF_BB2);
    int* DEG = (int*)(ws + OFF_DEG);
    int* OFFS = (int*)(ws + OFF_OFFS);
    int* CUR = (int*)(ws + OFF_CUR);
    int* CSR = (int*)(ws + OFF_CSR);

    float* Y = (float*)d_out;

    // 1. pack combined weights/biases
    pack_weights_kernel<<<(128 * 256 + 255) / 256, 256, 0, stream>>>(
        Wl1, bl1, Wr1, br1, Wl2, bl2, Wr2, br2, WB1, BB1, WB2, BB2);

    // 2. CSR build
    zero_int_kernel<<<(NN + 255) / 256, 256, 0, stream>>>(DEG, NN);
    hist_kernel<<<(EE + 255) / 256, 256, 0, stream>>>(tgts, DEG, EE);
    scan_kernel<<<1, 1024, 0, stream>>>(DEG, OFFS, CUR, NN);
    scatter_kernel<<<(EE + 255) / 256, 256, 0, stream>>>(srcs, tgts, CUR, CSR, EE);

    // 3. layer-1 GEMM: XLR1 = x @ [Wl1|Wr1] + [bl1|br1]
    {
        dim3 grid(256 / 64, (NN + 63) / 64);
        gemm_bias_kernel<<<grid, 256, 0, stream>>>(x, WB1, BB1, XLR1, NN, 256, 128);
    }

    // 4. layer-1 fused edge pass (+bias+LN+ELU) -> H1
    gat_edge1_kernel<<<(NN + 3) / 4, 256, 0, stream>>>(XLR1, OFFS, CSR, att1, b1, g1, be1, H1);

    // 5. layer-2 GEMM: XLR2 = H1 @ [Wl2|Wr2] + [bl2|br2]
    {
        dim3 grid(128 / 64, (NN + 63) / 64);
        gemm_bias_kernel<<<grid, 256, 0, stream>>>(H1, WB2, BB2, XLR2, NN, 80, 128);
    }

    // 6. layer-2 fused edge pass -> output
    gat_edge2_kernel<<<(NN + 3) / 4, 256, 0, stream>>>(XLR2, OFFS, CSR, att2, b2, Y);
}

// Round 2
// 338.846 us; speedup vs baseline: 1.2469x; 1.2469x over previous
//
#include <hip/hip_runtime.h>
#include <hip/hip_bf16.h>
#include <math.h>

// Problem constants
#define NN 50000
#define EE 800000
#define NEG_BIG (-3.0e38f)

// ---------------- workspace layout (bytes) ----------------
#define OFF_XLR1 ((size_t)0)                       // N*256 f32
#define SZ_XLR1  ((size_t)NN * 256 * 4)
#define OFF_H1   (OFF_XLR1 + SZ_XLR1)              // N*128 f32
#define SZ_H1    ((size_t)NN * 128 * 4)
#define OFF_XLR2 (OFF_H1 + SZ_H1)                  // N*80 f32
#define SZ_XLR2  ((size_t)NN * 80 * 4)
#define OFF_WB1  (OFF_XLR2 + SZ_XLR2)              // 128*256 f32
#define SZ_WB1   ((size_t)128 * 256 * 4)
#define OFF_BB1  (OFF_WB1 + SZ_WB1)                // 256 f32
#define SZ_BB1   ((size_t)1024)
#define OFF_WB2  (OFF_BB1 + SZ_BB1)                // 128*80 f32
#define SZ_WB2   ((size_t)128 * 80 * 4)
#define OFF_BB2  (OFF_WB2 + SZ_WB2)                // 80 f32 (pad)
#define SZ_BB2   ((size_t)512)
#define OFF_DEG  (OFF_BB2 + SZ_BB2)                // N int
#define SZ_DEG   ((size_t)NN * 4)
#define OFF_OFFS (OFF_DEG + SZ_DEG)                // (N+1) int (pad)
#define SZ_OFFS  ((size_t)((NN + 1) * 4 + 252) / 256 * 256)
#define OFF_CUR  (OFF_OFFS + SZ_OFFS)              // N int
#define SZ_CUR   ((size_t)NN * 4)
#define OFF_CSR  (OFF_CUR + SZ_CUR)                // E int
#define SZ_CSR   ((size_t)EE * 4)

// ---------------- small utility kernels ----------------
__global__ void zero_int_kernel(int* __restrict__ p, int n) {
    int i = blockIdx.x * blockDim.x + threadIdx.x;
    if (i < n) p[i] = 0;
}

__global__ void pack_weights_kernel(
    const float* __restrict__ Wl1, const float* __restrict__ bl1,
    const float* __restrict__ Wr1, const float* __restrict__ br1,
    const float* __restrict__ Wl2, const float* __restrict__ bl2,
    const float* __restrict__ Wr2, const float* __restrict__ br2,
    float* __restrict__ WB1, float* __restrict__ BB1,
    float* __restrict__ WB2, float* __restrict__ BB2) {
    int i = blockIdx.x * blockDim.x + threadIdx.x;
    if (i < 128 * 256) {
        int k = i >> 8, j = i & 255;
        WB1[i] = (j < 128) ? Wl1[k * 128 + j] : Wr1[k * 128 + j - 128];
    }
    if (i < 256) BB1[i] = (i < 128) ? bl1[i] : br1[i - 128];
    if (i < 128 * 80) {
        int k = i / 80, j = i % 80;
        WB2[i] = (j < 40) ? Wl2[k * 40 + j] : Wr2[k * 40 + j - 40];
    }
    if (i < 80) BB2[i] = (i < 40) ? bl2[i] : br2[i - 40];
}

__global__ void hist_kernel(const int* __restrict__ tgts, int* __restrict__ deg, int e_) {
    int e = blockIdx.x * blockDim.x + threadIdx.x;
    if (e < e_) atomicAdd(&deg[tgts[e]], 1);
}

// single-block inclusive scan over deg -> off[N+1], cur[i]=off[i]
__global__ __launch_bounds__(1024) void scan_kernel(
    const int* __restrict__ deg, int* __restrict__ off, int* __restrict__ cur, int n) {
    __shared__ int wsum[16];
    int carry = 0;
    int lane = threadIdx.x & 63, w = threadIdx.x >> 6;
    if (threadIdx.x == 0) off[0] = 0;
    for (int base = 0; base < n; base += 1024) {
        __syncthreads();
        int i = base + threadIdx.x;
        int v = (i < n) ? deg[i] : 0;
        int incl = v;
#pragma unroll
        for (int d = 1; d < 64; d <<= 1) {
            int t = __shfl_up(incl, d, 64);
            if (lane >= d) incl += t;
        }
        if (lane == 63) wsum[w] = incl;
        __syncthreads();
        if (threadIdx.x < 16) {
            int x = wsum[threadIdx.x];
#pragma unroll
            for (int d = 1; d < 16; d <<= 1) {
                int t = __shfl_up(x, d, 16);
                if ((int)threadIdx.x >= d) x += t;
            }
            wsum[threadIdx.x] = x;
        }
        __syncthreads();
        int add = (w > 0) ? wsum[w - 1] : 0;
        int inclTot = incl + add;
        if (i < n) {
            off[i + 1] = carry + inclTot;
            cur[i] = carry + inclTot - v;
        }
        carry += wsum[15];
    }
}

__global__ void scatter_kernel(const int* __restrict__ srcs, const int* __restrict__ tgts,
                               int* __restrict__ cur, int* __restrict__ csr, int e_) {
    int e = blockIdx.x * blockDim.x + threadIdx.x;
    if (e < e_) {
        int t = tgts[e];
        int pos = atomicAdd(&cur[t], 1);
        csr[pos] = srcs[e];
    }
}

// ---------------- f32 GEMM: C[M,N] = A[M,K] @ B[K,N] + bias[N] ----------------
__global__ __launch_bounds__(256) void gemm_bias_kernel(
    const float* __restrict__ A, const float* __restrict__ B,
    const float* __restrict__ bias, float* __restrict__ C,
    int M, int N, int K) {
    __shared__ float As[16][68];
    __shared__ float Bs[16][64];
    int tid = threadIdx.x;
    int r0 = blockIdx.y * 64;
    int n0 = blockIdx.x * 64;
    int trow = tid >> 4, tcol = tid & 15;
    int arow = tid >> 2;
    int akq = (tid & 3) << 2;
    int bk = tid >> 4;
    int bnq = (tid & 15) << 2;
    float acc[4][4] = {};
    for (int k0 = 0; k0 < K; k0 += 16) {
        float4 av = make_float4(0.f, 0.f, 0.f, 0.f);
        if (r0 + arow < M) av = *(const float4*)&A[(size_t)(r0 + arow) * K + k0 + akq];
        As[akq + 0][arow] = av.x;
        As[akq + 1][arow] = av.y;
        As[akq + 2][arow] = av.z;
        As[akq + 3][arow] = av.w;
        float4 bv;
        int bn = n0 + bnq;
        if (bn + 3 < N) {
            bv = *(const float4*)&B[(size_t)(k0 + bk) * N + bn];
        } else {
            float t0 = (bn + 0 < N) ? B[(size_t)(k0 + bk) * N + bn + 0] : 0.f;
            float t1 = (bn + 1 < N) ? B[(size_t)(k0 + bk) * N + bn + 1] : 0.f;
            float t2 = (bn + 2 < N) ? B[(size_t)(k0 + bk) * N + bn + 2] : 0.f;
            float t3 = (bn + 3 < N) ? B[(size_t)(k0 + bk) * N + bn + 3] : 0.f;
            bv = make_float4(t0, t1, t2, t3);
        }
        *(float4*)&Bs[bk][bnq] = bv;
        __syncthreads();
#pragma unroll
        for (int k = 0; k < 16; ++k) {
            float4 a = *(const float4*)&As[k][trow << 2];
            float4 b = *(const float4*)&Bs[k][tcol << 2];
            float ar[4] = {a.x, a.y, a.z, a.w};
            float br[4] = {b.x, b.y, b.z, b.w};
#pragma unroll
            for (int i = 0; i < 4; ++i)
#pragma unroll
                for (int j = 0; j < 4; ++j) acc[i][j] = fmaf(ar[i], br[j], acc[i][j]);
        }
        __syncthreads();
    }
#pragma unroll
    for (int i = 0; i < 4; ++i) {
        int r = r0 + (trow << 2) + i;
        if (r >= M) break;
#pragma unroll
        for (int j = 0; j < 4; ++j) {
            int c = n0 + (tcol << 2) + j;
            if (c < N) C[(size_t)r * N + c] = acc[i][j] + bias[c];
        }
    }
}

__device__ __forceinline__ float lrelu02(float h) { return fmaxf(h, 0.2f * h); }

// ---------------- layer-1 fused edge kernel (4 edges x 16 lanes per wave) ----
// Lane (grp=lane>>4, sub=lane&15) holds channels [sub*8, sub*8+8) of edge grp.
// Those 8 channels are all inside head sub>>2, so online-softmax state
// (m, s, acc[8]) is fully per-lane; groups merge at the end via shfl_xor 16/32.
__global__ __launch_bounds__(256) void gat_edge1_kernel(
    const float* __restrict__ XLR, const int* __restrict__ off, const int* __restrict__ csr,
    const float* __restrict__ att, const float* __restrict__ b1,
    const float* __restrict__ g1, const float* __restrict__ be1,
    float* __restrict__ H1) {
    int wid = threadIdx.x >> 6;
    int lane = threadIdx.x & 63;
    int node = blockIdx.x * 4 + wid;
    if (node >= NN) return;
    int grp = lane >> 4;
    int sub = lane & 15;
    int cbase = sub << 3;  // channel base (8 per lane)
    const float* xrrow = &XLR[(size_t)node * 256 + 128];
    float4 xrA = *(const float4*)&xrrow[cbase];
    float4 xrB = *(const float4*)&xrrow[cbase + 4];
    float4 atA = *(const float4*)&att[cbase];
    float4 atB = *(const float4*)&att[cbase + 4];
    float m = NEG_BIG, s = 0.f;
    float acc[8] = {};
    int jb = off[node], je = off[node + 1];
    int nb = (je - jb + 3) >> 2;
    for (int k = 0; k < nb; ++k) {
        int eidx = jb + (k << 2) + grp;
        bool valid = eidx < je;
        int src = valid ? csr[eidx] : 0;
        const float* xlrow = &XLR[(size_t)src * 256];
        float4 xlA = *(const float4*)&xlrow[cbase];
        float4 xlB = *(const float4*)&xlrow[cbase + 4];
        // score partial over this lane's 8 channels
        float t = lrelu02(xlA.x + xrA.x) * atA.x;
        t = fmaf(lrelu02(xlA.y + xrA.y), atA.y, t);
        t = fmaf(lrelu02(xlA.z + xrA.z), atA.z, t);
        t = fmaf(lrelu02(xlA.w + xrA.w), atA.w, t);
        t = fmaf(lrelu02(xlB.x + xrB.x), atB.x, t);
        t = fmaf(lrelu02(xlB.y + xrB.y), atB.y, t);
        t = fmaf(lrelu02(xlB.z + xrB.z), atB.z, t);
        t = fmaf(lrelu02(xlB.w + xrB.w), atB.w, t);
        // reduce over the 4 subs of this head (lanes differing in bits 0..1)
        t += __shfl_xor(t, 1, 64);
        t += __shfl_xor(t, 2, 64);
        if (valid) {
            float nm = fmaxf(m, t);
            float sc = __expf(m - nm);
            float p = __expf(t - nm);
            acc[0] = acc[0] * sc + p * xlA.x;
            acc[1] = acc[1] * sc + p * xlA.y;
            acc[2] = acc[2] * sc + p * xlA.z;
            acc[3] = acc[3] * sc + p * xlA.w;
            acc[4] = acc[4] * sc + p * xlB.x;
            acc[5] = acc[5] * sc + p * xlB.y;
            acc[6] = acc[6] * sc + p * xlB.z;
            acc[7] = acc[7] * sc + p * xlB.w;
            s = s * sc + p;
            m = nm;
        }
    }
    // merge the 4 groups' online-softmax states
#pragma unroll
    for (int d = 16; d <= 32; d <<= 1) {
        float mo = __shfl_xor(m, d, 64);
        float so = __shfl_xor(s, d, 64);
        float ao[8];
#pragma unroll
        for (int j = 0; j < 8; ++j) ao[j] = __shfl_xor(acc[j], d, 64);
        float nm = fmaxf(m, mo);
        float sa = __expf(m - nm), sb = __expf(mo - nm);
#pragma unroll
        for (int j = 0; j < 8; ++j) acc[j] = acc[j] * sa + ao[j] * sb;
        s = s * sa + so * sb;
        m = nm;
    }
    float inv = 1.f / (s + 1e-16f);
    float4 bA = *(const float4*)&b1[cbase];
    float4 bB = *(const float4*)&b1[cbase + 4];
    float o[8];
    o[0] = acc[0] * inv + bA.x;
    o[1] = acc[1] * inv + bA.y;
    o[2] = acc[2] * inv + bA.z;
    o[3] = acc[3] * inv + bA.w;
    o[4] = acc[4] * inv + bB.x;
    o[5] = acc[5] * inv + bB.y;
    o[6] = acc[6] * inv + bB.z;
    o[7] = acc[7] * inv + bB.w;
    // LayerNorm over 128 channels: per-lane 8 + reduce over 16 subs
    float sum = 0.f, sq = 0.f;
#pragma unroll
    for (int j = 0; j < 8; ++j) {
        sum += o[j];
        sq = fmaf(o[j], o[j], sq);
    }
#pragma unroll
    for (int d = 1; d <= 8; d <<= 1) {
        sum += __shfl_xor(sum, d, 64);
        sq += __shfl_xor(sq, d, 64);
    }
    float mu = sum * (1.f / 128.f);
    float var = sq * (1.f / 128.f) - mu * mu;
    float rs = rsqrtf(var + 1e-5f);
    if (grp == 0) {
        float4 gA = *(const float4*)&g1[cbase];
        float4 gB = *(const float4*)&g1[cbase + 4];
        float4 eA = *(const float4*)&be1[cbase];
        float4 eB = *(const float4*)&be1[cbase + 4];
        float y[8];
        y[0] = (o[0] - mu) * rs * gA.x + eA.x;
        y[1] = (o[1] - mu) * rs * gA.y + eA.y;
        y[2] = (o[2] - mu) * rs * gA.z + eA.z;
        y[3] = (o[3] - mu) * rs * gA.w + eA.w;
        y[4] = (o[4] - mu) * rs * gB.x + eB.x;
        y[5] = (o[5] - mu) * rs * gB.y + eB.y;
        y[6] = (o[6] - mu) * rs * gB.z + eB.z;
        y[7] = (o[7] - mu) * rs * gB.w + eB.w;
#pragma unroll
        for (int j = 0; j < 8; ++j) y[j] = y[j] > 0.f ? y[j] : expm1f(y[j]);
        float* hrow = &H1[(size_t)node * 128 + cbase];
        *(float4*)&hrow[0] = make_float4(y[0], y[1], y[2], y[3]);
        *(float4*)&hrow[4] = make_float4(y[4], y[5], y[6], y[7]);
    }
}

// ---------------- layer-2 fused edge kernel (4 edges x 16 lanes) -------------
// Single head, C=40. Subs 0..9 hold 4 channels each (float4); subs 10..15 idle
// in the channel math but participate in shuffles with zero contributions.
__global__ __launch_bounds__(256) void gat_edge2_kernel(
    const float* __restrict__ XLR2, const int* __restrict__ off, const int* __restrict__ csr,
    const float* __restrict__ att2, const float* __restrict__ b2,
    float* __restrict__ Y) {
    int wid = threadIdx.x >> 6;
    int lane = threadIdx.x & 63;
    int node = blockIdx.x * 4 + wid;
    if (node >= NN) return;
    int grp = lane >> 4;
    int sub = lane & 15;
    bool chact = sub < 10;
    int cbase = sub << 2;
    const size_t nb_ = (size_t)node * 80;
    float4 xr = make_float4(0.f, 0.f, 0.f, 0.f);
    float4 at = make_float4(0.f, 0.f, 0.f, 0.f);
    if (chact) {
        xr = *(const float4*)&XLR2[nb_ + 40 + cbase];
        at = *(const float4*)&att2[cbase];
    }
    float m = NEG_BIG, s = 0.f;
    float acc[4] = {};
    int jb = off[node], je = off[node + 1];
    int nb = (je - jb + 3) >> 2;
    for (int k = 0; k < nb; ++k) {
        int eidx = jb + (k << 2) + grp;
        bool valid = eidx < je;
        int src = valid ? csr[eidx] : 0;
        float4 xl = make_float4(0.f, 0.f, 0.f, 0.f);
        if (chact) xl = *(const float4*)&XLR2[(size_t)src * 80 + cbase];
        float t = lrelu02(xl.x + xr.x) * at.x;
        t = fmaf(lrelu02(xl.y + xr.y), at.y, t);
        t = fmaf(lrelu02(xl.z + xr.z), at.z, t);
        t = fmaf(lrelu02(xl.w + xr.w), at.w, t);
        // reduce over 16 subs (single head)
        t += __shfl_xor(t, 1, 64);
        t += __shfl_xor(t, 2, 64);
        t += __shfl_xor(t, 4, 64);
        t += __shfl_xor(t, 8, 64);
        if (valid) {
            float nm = fmaxf(m, t);
            float sc = __expf(m - nm);
            float p = __expf(t - nm);
            acc[0] = acc[0] * sc + p * xl.x;
            acc[1] = acc[1] * sc + p * xl.y;
            acc[2] = acc[2] * sc + p * xl.z;
            acc[3] = acc[3] * sc + p * xl.w;
            s = s * sc + p;
            m = nm;
        }
    }
#pragma unroll
    for (int d = 16; d <= 32; d <<= 1) {
        float mo = __shfl_xor(m, d, 64);
        float so = __shfl_xor(s, d, 64);
        float a0 = __shfl_xor(acc[0], d, 64);
        float a1 = __shfl_xor(acc[1], d, 64);
        float a2 = __shfl_xor(acc[2], d, 64);
        float a3 = __shfl_xor(acc[3], d, 64);
        float nm = fmaxf(m, mo);
        float sa = __expf(m - nm), sb = __expf(mo - nm);
        acc[0] = acc[0] * sa + a0 * sb;
        acc[1] = acc[1] * sa + a1 * sb;
        acc[2] = acc[2] * sa + a2 * sb;
        acc[3] = acc[3] * sa + a3 * sb;
        s = s * sa + so * sb;
        m = nm;
    }
    if (grp == 0 && chact) {
        float inv = 1.f / (s + 1e-16f);
        float4 bb = *(const float4*)&b2[cbase];
        float4 y;
        y.x = acc[0] * inv + bb.x;
        y.y = acc[1] * inv + bb.y;
        y.z = acc[2] * inv + bb.z;
        y.w = acc[3] * inv + bb.w;
        *(float4*)&Y[(size_t)node * 40 + cbase] = y;
    }
}

// ---------------- launch ----------------
extern "C" void kernel_launch(void* const* d_in, const int* in_sizes, int n_in,
                              void* d_out, int out_size, void* d_ws, size_t ws_size,
                              hipStream_t stream) {
    const float* x = (const float*)d_in[0];
    const int* ei = (const int*)d_in[1];
    const float* Wl1 = (const float*)d_in[2];
    const float* bl1 = (const float*)d_in[3];
    const float* Wr1 = (const float*)d_in[4];
    const float* br1 = (const float*)d_in[5];
    const float* att1 = (const float*)d_in[6];
    const float* b1 = (const float*)d_in[7];
    const float* g1 = (const float*)d_in[8];
    const float* be1 = (const float*)d_in[9];
    const float* Wl2 = (const float*)d_in[10];
    const float* bl2 = (const float*)d_in[11];
    const float* Wr2 = (const float*)d_in[12];
    const float* br2 = (const float*)d_in[13];
    const float* att2 = (const float*)d_in[14];
    const float* b2 = (const float*)d_in[15];

    const int* srcs = ei;
    const int* tgts = ei + EE;

    char* ws = (char*)d_ws;
    float* XLR1 = (float*)(ws + OFF_XLR1);
    float* H1 = (float*)(ws + OFF_H1);
    float* XLR2 = (float*)(ws + OFF_XLR2);
    float* WB1 = (float*)(ws + OFF_WB1);
    float* BB1 = (float*)(ws + OFF_BB1);
    float* WB2 = (float*)(ws + OFF_WB2);
    float* BB2 = (float*)(ws + OFF_BB2);
    int* DEG = (int*)(ws + OFF_DEG);
    int* OFFS = (int*)(ws + OFF_OFFS);
    int* CUR = (int*)(ws + OFF_CUR);
    int* CSR = (int*)(ws + OFF_CSR);

    float* Y = (float*)d_out;

    pack_weights_kernel<<<(128 * 256 + 255) / 256, 256, 0, stream>>>(
        Wl1, bl1, Wr1, br1, Wl2, bl2, Wr2, br2, WB1, BB1, WB2, BB2);

    zero_int_kernel<<<(NN + 255) / 256, 256, 0, stream>>>(DEG, NN);
    hist_kernel<<<(EE + 255) / 256, 256, 0, stream>>>(tgts, DEG, EE);
    scan_kernel<<<1, 1024, 0, stream>>>(DEG, OFFS, CUR, NN);
    scatter_kernel<<<(EE + 255) / 256, 256, 0, stream>>>(srcs, tgts, CUR, CSR, EE);

    {
        dim3 grid(256 / 64, (NN + 63) / 64);
        gemm_bias_kernel<<<grid, 256, 0, stream>>>(x, WB1, BB1, XLR1, NN, 256, 128);
    }

    gat_edge1_kernel<<<(NN + 3) / 4, 256, 0, stream>>>(XLR1, OFFS, CSR, att1, b1, g1, be1, H1);

    {
        dim3 grid(128 / 64, (NN + 63) / 64);
        gemm_bias_kernel<<<grid, 256, 0, stream>>>(H1, WB2, BB2, XLR2, NN, 80, 128);
    }

    gat_edge2_kernel<<<(NN + 3) / 4, 256, 0, stream>>>(XLR2, OFFS, CSR, att2, b2, Y);
}